// Round 1
// baseline (2385.643 us; speedup 1.0000x reference)
//
#include <hip/hip_runtime.h>
#include <math.h>

typedef __attribute__((ext_vector_type(8))) short short8;
typedef __attribute__((ext_vector_type(4))) float f32x4;

__device__ __forceinline__ unsigned short f2bf(float f) {
  unsigned u = __float_as_uint(f);
  u += 0x7FFFu + ((u >> 16) & 1u);          // RTN-even
  return (unsigned short)(u >> 16);
}
__device__ __forceinline__ float bf2f(unsigned short h) {
  return __uint_as_float(((unsigned)h) << 16);
}

// ---------------- workspace layout (bytes) ----------------
static constexpr unsigned OFF_WQKV1 = 0;          // 768x256 bf16
static constexpr unsigned OFF_BQKV1 = 393216;     // 768 f32
static constexpr unsigned OFF_WQ2   = 396288;     // 256x256 bf16
static constexpr unsigned OFF_BQ2   = 527360;     // 256 f32
static constexpr unsigned OFF_WKV2  = 528384;     // 512x256 bf16
static constexpr unsigned OFF_BKV2  = 790528;     // 512 f32
static constexpr unsigned OFF_WP1   = 792576;     // 256x256 bf16
static constexpr unsigned OFF_BP1   = 923648;
static constexpr unsigned OFF_WP2   = 924672;
static constexpr unsigned OFF_BP2   = 1055744;
static constexpr unsigned OFF_WFC1  = 1056768;    // 1024x256 bf16
static constexpr unsigned OFF_BFC1  = 1581056;    // 1024 f32
static constexpr unsigned OFF_WFC2  = 1585152;    // 256x1024 bf16
static constexpr unsigned OFF_BFC2  = 2109440;
static constexpr unsigned OFF_BIAS1 = 2110464;    // 8x64x64 f32
static constexpr unsigned OFF_BIAS2 = 2241536;    // 8x64x64 f32

static constexpr size_t OFF_X1  = 4194304;                    // f32 [131072][256] = 128MB
static constexpr size_t OFF_QKV = OFF_X1  + 134217728ull;     // bf16 [131072][768] = 192MB (also Q2 / gelu buffer)
static constexpr size_t OFF_KV2 = OFF_QKV + 67108864ull;      // bf16 [131072][512]
static constexpr size_t OFF_HB  = OFF_QKV + 201326592ull;     // bf16 [131072][256] = 64MB
static constexpr size_t OFF_HA  = OFF_HB  + 67108864ull;      // bf16 [131072][256] = 64MB
// total ws usage: OFF_HA + 64MB = 473,956,352 bytes

// ---------------- prep: weights->bf16 (+fold q scale), bias tables ----------------
__global__ __launch_bounds__(256) void prep_kernel(
    const float* __restrict__ a1_qw, const float* __restrict__ a1_qb,
    const float* __restrict__ a1_kvw, const float* __restrict__ a1_kvb,
    const float* __restrict__ a1_pw, const float* __restrict__ a1_pb,
    const float* __restrict__ a1_tab,
    const float* __restrict__ a2_qw, const float* __restrict__ a2_qb,
    const float* __restrict__ a2_kvw, const float* __restrict__ a2_kvb,
    const float* __restrict__ a2_pw, const float* __restrict__ a2_pb,
    const float* __restrict__ a2_tab,
    const float* __restrict__ fc1w, const float* __restrict__ fc1b,
    const float* __restrict__ fc2w, const float* __restrict__ fc2b,
    char* __restrict__ ws)
{
  int idx = blockIdx.x * 256 + threadIdx.x;
  const float SC = 0.17677669529663687f;  // 32^-0.5
  if (idx < 196608) {                                    // WQKV1 [768][256]
    int o = idx >> 8, c = idx & 255;
    float v = (o < 256) ? a1_qw[o * 256 + c] * SC : a1_kvw[(o - 256) * 256 + c];
    ((unsigned short*)(ws + OFF_WQKV1))[idx] = f2bf(v);
    return;
  }
  idx -= 196608;
  if (idx < 768) {
    float v = (idx < 256) ? a1_qb[idx] * SC : a1_kvb[idx - 256];
    ((float*)(ws + OFF_BQKV1))[idx] = v; return;
  }
  idx -= 768;
  if (idx < 65536) { ((unsigned short*)(ws + OFF_WQ2))[idx] = f2bf(a2_qw[idx] * SC); return; }
  idx -= 65536;
  if (idx < 256)   { ((float*)(ws + OFF_BQ2))[idx] = a2_qb[idx] * SC; return; }
  idx -= 256;
  if (idx < 131072){ ((unsigned short*)(ws + OFF_WKV2))[idx] = f2bf(a2_kvw[idx]); return; }
  idx -= 131072;
  if (idx < 512)   { ((float*)(ws + OFF_BKV2))[idx] = a2_kvb[idx]; return; }
  idx -= 512;
  if (idx < 65536) { ((unsigned short*)(ws + OFF_WP1))[idx] = f2bf(a1_pw[idx]); return; }
  idx -= 65536;
  if (idx < 256)   { ((float*)(ws + OFF_BP1))[idx] = a1_pb[idx]; return; }
  idx -= 256;
  if (idx < 65536) { ((unsigned short*)(ws + OFF_WP2))[idx] = f2bf(a2_pw[idx]); return; }
  idx -= 65536;
  if (idx < 256)   { ((float*)(ws + OFF_BP2))[idx] = a2_pb[idx]; return; }
  idx -= 256;
  if (idx < 262144){ ((unsigned short*)(ws + OFF_WFC1))[idx] = f2bf(fc1w[idx]); return; }
  idx -= 262144;
  if (idx < 1024)  { ((float*)(ws + OFF_BFC1))[idx] = fc1b[idx]; return; }
  idx -= 1024;
  if (idx < 262144){ ((unsigned short*)(ws + OFF_WFC2))[idx] = f2bf(fc2w[idx]); return; }
  idx -= 262144;
  if (idx < 256)   { ((float*)(ws + OFF_BFC2))[idx] = fc2b[idx]; return; }
  idx -= 256;
  if (idx < 32768) {                                     // bias1[h][i][j]
    int h = idx >> 12, r = idx & 4095;
    int i = r >> 6, j = r & 63;
    int rel = ((i >> 3) - (j >> 3) + 7) * 15 + ((i & 7) - (j & 7) + 7);
    ((float*)(ws + OFF_BIAS1))[idx] = a1_tab[rel * 8 + h];
    return;
  }
  idx -= 32768;
  if (idx < 32768) {
    int h = idx >> 12, r = idx & 4095;
    int i = r >> 6, j = r & 63;
    int rel = ((i >> 3) - (j >> 3) + 7) * 15 + ((i & 7) - (j & 7) + 7);
    ((float*)(ws + OFF_BIAS2))[idx] = a2_tab[rel * 8 + h];
  }
}

// ---------------- LayerNorm (+optional roll(-4,-4)+window-partition), fp32->bf16 ----------------
template<int SHIFTED>
__global__ __launch_bounds__(256)
void ln_kernel(const float* __restrict__ in, const float* __restrict__ gw,
               const float* __restrict__ gb, unsigned short* __restrict__ out)
{
  const int token = blockIdx.x * 4 + (threadIdx.x >> 6);
  const int lane  = threadIdx.x & 63;
  const float4 v = *(const float4*)&in[token * 256 + lane * 4];
  float s  = v.x + v.y + v.z + v.w;
  float sq = v.x * v.x + v.y * v.y + v.z * v.z + v.w * v.w;
  #pragma unroll
  for (int m = 1; m < 64; m <<= 1) { s += __shfl_xor(s, m, 64); sq += __shfl_xor(sq, m, 64); }
  const float mean = s * 0.00390625f;
  const float var  = sq * 0.00390625f - mean * mean;
  const float rstd = rsqrtf(var + 1e-5f);
  const float4 wv = *(const float4*)&gw[lane * 4];
  const float4 bv = *(const float4*)&gb[lane * 4];
  int orow;
  if (SHIFTED) {
    const int bb = token >> 16;
    const int h  = (token >> 8) & 255;
    const int w  = token & 255;
    const int hs  = (h - 4) & 255;           // roll(-4): x[h] lands at shifted row h-4
    const int wsn = (w - 4) & 255;
    orow = (((bb << 10) + ((hs >> 3) << 5) + (wsn >> 3)) << 6) + ((hs & 7) << 3) + (wsn & 7);
  } else {
    orow = token;
  }
  ushort4 o;
  o.x = f2bf((v.x - mean) * rstd * wv.x + bv.x);
  o.y = f2bf((v.y - mean) * rstd * wv.y + bv.y);
  o.z = f2bf((v.z - mean) * rstd * wv.z + bv.z);
  o.w = f2bf((v.w - mean) * rstd * wv.w + bv.w);
  *(ushort4*)&out[orow * 256 + lane * 4] = o;
}

// ---------------- bf16 GEMM: C[M,N] = A[M,K] @ W[N,K]^T + bias, templated epilogue ----------------
// MODE 0: bias -> bf16 out          MODE 1: bias + exact GELU -> bf16 out
// MODE 2: bias + residual(resF) with window-row -> natural-row scatter (roll +4), f32 out (N must be 256)
// MODE 3: bias + residual(resF) natural rows, f32 out
template<int MODE>
__global__ __launch_bounds__(256)
void gemm_bt(const unsigned short* __restrict__ A, const unsigned short* __restrict__ W,
             const float* __restrict__ bias, int M, int N, int K,
             unsigned short* __restrict__ outB, float* outF, const float* resF)
{
  __shared__ unsigned short As[128 * 64];
  __shared__ unsigned short Bs[128 * 64];
  const int tid  = threadIdx.x;
  const int lane = tid & 63;
  const int wv   = tid >> 6;
  const int n0 = blockIdx.x * 128;
  const int m0 = blockIdx.y * 128;
  const int wm = (wv >> 1) * 64;
  const int wn = (wv & 1) * 64;
  const int lr = lane & 15;
  const int lk = (lane >> 4) * 8;

  f32x4 acc[4][4] = {};

  for (int k0 = 0; k0 < K; k0 += 64) {
    #pragma unroll
    for (int s = 0; s < 4; s++) {            // stage 128x64 bf16 of A and W, XOR-swizzled
      const int u = tid + s * 256;
      const int r = u >> 3;
      const int c = (u & 7) * 8;
      const int sw = (r & 7) << 3;           // swizzle 16B chunks within the 128B row
      *(short8*)&As[(r * 64 + c) ^ sw] = *(const short8*)&A[(m0 + r) * K + k0 + c];
      *(short8*)&Bs[(r * 64 + c) ^ sw] = *(const short8*)&W[(n0 + r) * K + k0 + c];
    }
    __syncthreads();
    #pragma unroll
    for (int kk = 0; kk < 64; kk += 32) {
      short8 af[4], bf[4];
      #pragma unroll
      for (int i = 0; i < 4; i++) {
        const int ra = wm + i * 16 + lr;
        const int rb = wn + i * 16 + lr;
        af[i] = *(const short8*)&As[(ra * 64 + kk + lk) ^ ((ra & 7) << 3)];
        bf[i] = *(const short8*)&Bs[(rb * 64 + kk + lk) ^ ((rb & 7) << 3)];
      }
      #pragma unroll
      for (int i = 0; i < 4; i++)
        #pragma unroll
        for (int j = 0; j < 4; j++)
          acc[i][j] = __builtin_amdgcn_mfma_f32_16x16x32_bf16(af[i], bf[j], acc[i][j], 0, 0, 0);
    }
    __syncthreads();
  }

  // epilogue: C layout col=lane&15, row=(lane>>4)*4+reg  [m89/m91-verified]
  #pragma unroll
  for (int j = 0; j < 4; j++) {
    const int col = n0 + wn + j * 16 + lr;
    const float bv = bias[col];
    #pragma unroll
    for (int i = 0; i < 4; i++) {
      #pragma unroll
      for (int r = 0; r < 4; r++) {
        const int row = m0 + wm + i * 16 + (lane >> 4) * 4 + r;
        float v = acc[i][j][r] + bv;
        if (MODE == 0) {
          outB[row * N + col] = f2bf(v);
        } else if (MODE == 1) {
          float g = 0.5f * v * (1.0f + erff(v * 0.70710678118654752f));
          outB[row * N + col] = f2bf(g);
        } else if (MODE == 2) {
          const int i6 = row & 63, wn_ = row >> 6;
          const int bb = wn_ >> 10, wi = wn_ & 1023;
          const int hs  = ((wi >> 5) << 3) + (i6 >> 3);
          const int wsn = ((wi & 31) << 3) + (i6 & 7);
          const int hh = (hs + 4) & 255, ww = (wsn + 4) & 255;  // reverse roll (+4)
          const int nat = (bb << 16) + (hh << 8) + ww;
          outF[nat * 256 + col] = resF[nat * 256 + col] + v;
        } else {
          outF[row * N + col] = resF[row * N + col] + v;
        }
      }
    }
  }
}

// ---------------- windowed attention (VALU fp32, 1 block = 1 window of 64 tokens) ----------------
__global__ __launch_bounds__(256)
void attn_kernel(const unsigned short* __restrict__ Qm, int sq,
                 const unsigned short* __restrict__ Km,
                 const unsigned short* __restrict__ Vm, int skv,
                 const float* __restrict__ mask, const float* __restrict__ biasT,
                 unsigned short* __restrict__ outO)
{
  __shared__ unsigned short Kl[64 * 256];
  __shared__ unsigned short Vl[64 * 256];
  const int win = blockIdx.x;
  const int wi  = win & 1023;
  const int tid = threadIdx.x;
  const int t = tid & 63;
  const int g = tid >> 6;

  for (int u = tid; u < 2048; u += 256) {     // stage K,V (bf16) into LDS
    const int j = u >> 5;
    const int c = (u & 31) * 8;
    *(short8*)&Kl[j * 256 + c] = *(const short8*)&Km[(win * 64 + j) * skv + c];
    *(short8*)&Vl[j * 256 + c] = *(const short8*)&Vm[(win * 64 + j) * skv + c];
  }
  __syncthreads();

  const float* mrow = &mask[wi * 4096 + t * 64];

  #pragma unroll
  for (int hh = 0; hh < 2; hh++) {
    const int h = g * 2 + hh;
    float qr[32];
    const unsigned short* qp = &Qm[(win * 64 + t) * sq + h * 32];
    #pragma unroll
    for (int c = 0; c < 4; c++) {
      const short8 qv = *(const short8*)&qp[c * 8];
      #pragma unroll
      for (int e = 0; e < 8; e++) qr[c * 8 + e] = bf2f((unsigned short)qv[e]);
    }
    const float* brow = &biasT[h * 4096 + t * 64];
    float s[64];
    #pragma unroll
    for (int j = 0; j < 64; j++) {            // scores (scale pre-folded into Q)
      const unsigned short* kp = &Kl[j * 256 + h * 32];  // wave-uniform -> broadcast read
      float a = 0.f;
      #pragma unroll
      for (int c = 0; c < 4; c++) {
        const short8 k8 = *(const short8*)&kp[c * 8];
        #pragma unroll
        for (int e = 0; e < 8; e++) a = fmaf(qr[c * 8 + e], bf2f((unsigned short)k8[e]), a);
      }
      s[j] = a + brow[j] + mrow[j];
    }
    float mx = -1e30f;
    #pragma unroll
    for (int j = 0; j < 64; j++) mx = fmaxf(mx, s[j]);
    float sum = 0.f;
    #pragma unroll
    for (int j = 0; j < 64; j++) { const float e = __expf(s[j] - mx); s[j] = e; sum += e; }
    const float inv = 1.f / sum;
    float o[32];
    #pragma unroll
    for (int d = 0; d < 32; d++) o[d] = 0.f;
    #pragma unroll
    for (int j = 0; j < 64; j++) {
      const float p = s[j];
      const unsigned short* vp = &Vl[j * 256 + h * 32];
      #pragma unroll
      for (int c = 0; c < 4; c++) {
        const short8 v8 = *(const short8*)&vp[c * 8];
        #pragma unroll
        for (int e = 0; e < 8; e++) o[c * 8 + e] = fmaf(p, bf2f((unsigned short)v8[e]), o[c * 8 + e]);
      }
    }
    unsigned short* op = &outO[(win * 64 + t) * 256 + h * 32];
    #pragma unroll
    for (int c = 0; c < 4; c++) {
      short8 ov;
      #pragma unroll
      for (int e = 0; e < 8; e++) ov[e] = (short)f2bf(o[c * 8 + e] * inv);
      *(short8*)&op[c * 8] = ov;
    }
  }
}

// ---------------- launch ----------------
extern "C" void kernel_launch(void* const* d_in, const int* in_sizes, int n_in,
                              void* d_out, int out_size, void* d_ws, size_t ws_size,
                              hipStream_t stream)
{
  const float* x       = (const float*)d_in[0];
  const float* akv     = (const float*)d_in[1];
  const float* mask_q  = (const float*)d_in[2];
  const float* mask_kv = (const float*)d_in[3];
  const float* n1w = (const float*)d_in[4];
  const float* n1b = (const float*)d_in[5];
  const float* n2w = (const float*)d_in[6];
  const float* n2b = (const float*)d_in[7];
  const float* n3w = (const float*)d_in[8];
  const float* n3b = (const float*)d_in[9];
  const float* nkvw = (const float*)d_in[10];
  const float* nkvb = (const float*)d_in[11];

  char* ws = (char*)d_ws;
  const unsigned short* WQKV1 = (const unsigned short*)(ws + OFF_WQKV1);
  const float*          BQKV1 = (const float*)(ws + OFF_BQKV1);
  const unsigned short* WQ2   = (const unsigned short*)(ws + OFF_WQ2);
  const float*          BQ2   = (const float*)(ws + OFF_BQ2);
  const unsigned short* WKV2  = (const unsigned short*)(ws + OFF_WKV2);
  const float*          BKV2  = (const float*)(ws + OFF_BKV2);
  const unsigned short* WP1   = (const unsigned short*)(ws + OFF_WP1);
  const float*          BP1   = (const float*)(ws + OFF_BP1);
  const unsigned short* WP2   = (const unsigned short*)(ws + OFF_WP2);
  const float*          BP2   = (const float*)(ws + OFF_BP2);
  const unsigned short* WFC1  = (const unsigned short*)(ws + OFF_WFC1);
  const float*          BFC1  = (const float*)(ws + OFF_BFC1);
  const unsigned short* WFC2  = (const unsigned short*)(ws + OFF_WFC2);
  const float*          BFC2  = (const float*)(ws + OFF_BFC2);
  const float* BIAS1 = (const float*)(ws + OFF_BIAS1);
  const float* BIAS2 = (const float*)(ws + OFF_BIAS2);

  float*          x1  = (float*)(ws + OFF_X1);
  unsigned short* qkv = (unsigned short*)(ws + OFF_QKV);   // QKV1 / Q2 / gelu buffer
  unsigned short* kv2 = (unsigned short*)(ws + OFF_KV2);
  unsigned short* hB  = (unsigned short*)(ws + OFF_HB);
  unsigned short* hA  = (unsigned short*)(ws + OFF_HA);
  float* out = (float*)d_out;

  prep_kernel<<<4365, 256, 0, stream>>>(
      (const float*)d_in[12], (const float*)d_in[13], (const float*)d_in[14], (const float*)d_in[15],
      (const float*)d_in[16], (const float*)d_in[17], (const float*)d_in[18],
      (const float*)d_in[19], (const float*)d_in[20], (const float*)d_in[21], (const float*)d_in[22],
      (const float*)d_in[23], (const float*)d_in[24], (const float*)d_in[25],
      (const float*)d_in[26], (const float*)d_in[27], (const float*)d_in[28], (const float*)d_in[29],
      ws);

  // ---- shifted-window self attention ----
  ln_kernel<1><<<32768, 256, 0, stream>>>(x, n1w, n1b, hA);
  gemm_bt<0><<<dim3(6, 1024), 256, 0, stream>>>(hA, WQKV1, BQKV1, 131072, 768, 256, qkv, nullptr, nullptr);
  attn_kernel<<<2048, 256, 0, stream>>>(qkv, 768, qkv + 256, qkv + 512, 768, mask_q, BIAS1, hA);
  gemm_bt<2><<<dim3(2, 1024), 256, 0, stream>>>(hA, WP1, BP1, 131072, 256, 256, nullptr, x1, x);

  // ---- shifted-window cross attention ----
  ln_kernel<1><<<32768, 256, 0, stream>>>(x1, n2w, n2b, hA);
  ln_kernel<1><<<32768, 256, 0, stream>>>(akv, nkvw, nkvb, hB);
  gemm_bt<0><<<dim3(2, 1024), 256, 0, stream>>>(hA, WQ2, BQ2, 131072, 256, 256, qkv, nullptr, nullptr);
  gemm_bt<0><<<dim3(4, 1024), 256, 0, stream>>>(hB, WKV2, BKV2, 131072, 512, 256, kv2, nullptr, nullptr);
  attn_kernel<<<2048, 256, 0, stream>>>(qkv, 256, kv2, kv2 + 256, 512, mask_kv, BIAS2, hA);
  gemm_bt<2><<<dim3(2, 1024), 256, 0, stream>>>(hA, WP2, BP2, 131072, 256, 256, nullptr, out, x1);

  // ---- MLP ----
  ln_kernel<0><<<32768, 256, 0, stream>>>(out, n3w, n3b, hA);
  gemm_bt<1><<<dim3(8, 1024), 256, 0, stream>>>(hA, WFC1, BFC1, 131072, 1024, 256, qkv, nullptr, nullptr);
  gemm_bt<3><<<dim3(2, 1024), 256, 0, stream>>>(qkv, WFC2, BFC2, 131072, 256, 1024, nullptr, out, out);
}

// Round 2
// 2083.444 us; speedup vs baseline: 1.1450x; 1.1450x over previous
//
#include <hip/hip_runtime.h>
#include <math.h>

typedef __attribute__((ext_vector_type(8))) short short8;
typedef __attribute__((ext_vector_type(4))) float f32x4;

__device__ __forceinline__ unsigned short f2bf(float f) {
  unsigned u = __float_as_uint(f);
  u += 0x7FFFu + ((u >> 16) & 1u);          // RTN-even
  return (unsigned short)(u >> 16);
}
__device__ __forceinline__ float bf2f(unsigned short h) {
  return __uint_as_float(((unsigned)h) << 16);
}
__device__ __forceinline__ void gload_lds16(const unsigned short* g, unsigned short* l) {
  __builtin_amdgcn_global_load_lds((const __attribute__((address_space(1))) void*)g,
                                   (__attribute__((address_space(3))) void*)l, 16, 0, 0);
}

// ---------------- workspace layout (bytes) ----------------
static constexpr unsigned OFF_WQKV1 = 0;          // 768x256 bf16
static constexpr unsigned OFF_BQKV1 = 393216;     // 768 f32
static constexpr unsigned OFF_WQ2   = 396288;     // 256x256 bf16
static constexpr unsigned OFF_BQ2   = 527360;     // 256 f32
static constexpr unsigned OFF_WKV2  = 528384;     // 512x256 bf16
static constexpr unsigned OFF_BKV2  = 790528;     // 512 f32
static constexpr unsigned OFF_WP1   = 792576;     // 256x256 bf16
static constexpr unsigned OFF_BP1   = 923648;
static constexpr unsigned OFF_WP2   = 924672;
static constexpr unsigned OFF_BP2   = 1055744;
static constexpr unsigned OFF_WFC1  = 1056768;    // 1024x256 bf16
static constexpr unsigned OFF_BFC1  = 1581056;    // 1024 f32
static constexpr unsigned OFF_WFC2  = 1585152;    // 256x1024 bf16
static constexpr unsigned OFF_BFC2  = 2109440;
static constexpr unsigned OFF_BIAS1 = 2110464;    // 8x64x64 f32
static constexpr unsigned OFF_BIAS2 = 2241536;    // 8x64x64 f32

static constexpr size_t OFF_X1  = 4194304;                    // f32 [131072][256] = 128MB
static constexpr size_t OFF_QKV = OFF_X1  + 134217728ull;     // bf16 [131072][768] (also Q2 / FC1 buffer)
static constexpr size_t OFF_KV2 = OFF_QKV + 67108864ull;      // bf16 [131072][512] (after Q2's 64MB)
static constexpr size_t OFF_HB  = OFF_QKV + 201326592ull;     // bf16 [131072][256]
static constexpr size_t OFF_HA  = OFF_HB  + 67108864ull;      // bf16 [131072][256]

// ---------------- prep: weights->bf16 (+fold q scale), bias tables ----------------
__global__ __launch_bounds__(256) void prep_kernel(
    const float* __restrict__ a1_qw, const float* __restrict__ a1_qb,
    const float* __restrict__ a1_kvw, const float* __restrict__ a1_kvb,
    const float* __restrict__ a1_pw, const float* __restrict__ a1_pb,
    const float* __restrict__ a1_tab,
    const float* __restrict__ a2_qw, const float* __restrict__ a2_qb,
    const float* __restrict__ a2_kvw, const float* __restrict__ a2_kvb,
    const float* __restrict__ a2_pw, const float* __restrict__ a2_pb,
    const float* __restrict__ a2_tab,
    const float* __restrict__ fc1w, const float* __restrict__ fc1b,
    const float* __restrict__ fc2w, const float* __restrict__ fc2b,
    char* __restrict__ ws)
{
  int idx = blockIdx.x * 256 + threadIdx.x;
  const float SC = 0.17677669529663687f;  // 32^-0.5
  if (idx < 196608) {                                    // WQKV1 [768][256]
    int o = idx >> 8, c = idx & 255;
    float v = (o < 256) ? a1_qw[o * 256 + c] * SC : a1_kvw[(o - 256) * 256 + c];
    ((unsigned short*)(ws + OFF_WQKV1))[idx] = f2bf(v);
    return;
  }
  idx -= 196608;
  if (idx < 768) {
    float v = (idx < 256) ? a1_qb[idx] * SC : a1_kvb[idx - 256];
    ((float*)(ws + OFF_BQKV1))[idx] = v; return;
  }
  idx -= 768;
  if (idx < 65536) { ((unsigned short*)(ws + OFF_WQ2))[idx] = f2bf(a2_qw[idx] * SC); return; }
  idx -= 65536;
  if (idx < 256)   { ((float*)(ws + OFF_BQ2))[idx] = a2_qb[idx] * SC; return; }
  idx -= 256;
  if (idx < 131072){ ((unsigned short*)(ws + OFF_WKV2))[idx] = f2bf(a2_kvw[idx]); return; }
  idx -= 131072;
  if (idx < 512)   { ((float*)(ws + OFF_BKV2))[idx] = a2_kvb[idx]; return; }
  idx -= 512;
  if (idx < 65536) { ((unsigned short*)(ws + OFF_WP1))[idx] = f2bf(a1_pw[idx]); return; }
  idx -= 65536;
  if (idx < 256)   { ((float*)(ws + OFF_BP1))[idx] = a1_pb[idx]; return; }
  idx -= 256;
  if (idx < 65536) { ((unsigned short*)(ws + OFF_WP2))[idx] = f2bf(a2_pw[idx]); return; }
  idx -= 65536;
  if (idx < 256)   { ((float*)(ws + OFF_BP2))[idx] = a2_pb[idx]; return; }
  idx -= 256;
  if (idx < 262144){ ((unsigned short*)(ws + OFF_WFC1))[idx] = f2bf(fc1w[idx]); return; }
  idx -= 262144;
  if (idx < 1024)  { ((float*)(ws + OFF_BFC1))[idx] = fc1b[idx]; return; }
  idx -= 1024;
  if (idx < 262144){ ((unsigned short*)(ws + OFF_WFC2))[idx] = f2bf(fc2w[idx]); return; }
  idx -= 262144;
  if (idx < 256)   { ((float*)(ws + OFF_BFC2))[idx] = fc2b[idx]; return; }
  idx -= 256;
  if (idx < 32768) {                                     // bias1[h][i][j]
    int h = idx >> 12, r = idx & 4095;
    int i = r >> 6, j = r & 63;
    int rel = ((i >> 3) - (j >> 3) + 7) * 15 + ((i & 7) - (j & 7) + 7);
    ((float*)(ws + OFF_BIAS1))[idx] = a1_tab[rel * 8 + h];
    return;
  }
  idx -= 32768;
  if (idx < 32768) {
    int h = idx >> 12, r = idx & 4095;
    int i = r >> 6, j = r & 63;
    int rel = ((i >> 3) - (j >> 3) + 7) * 15 + ((i & 7) - (j & 7) + 7);
    ((float*)(ws + OFF_BIAS2))[idx] = a2_tab[rel * 8 + h];
  }
}

// ---------------- LayerNorm (+optional roll(-4,-4)+window-partition), fp32->bf16 ----------------
template<int SHIFTED>
__global__ __launch_bounds__(256)
void ln_kernel(const float* __restrict__ in, const float* __restrict__ gw,
               const float* __restrict__ gb, unsigned short* __restrict__ out)
{
  const int token = blockIdx.x * 4 + (threadIdx.x >> 6);
  const int lane  = threadIdx.x & 63;
  const float4 v = *(const float4*)&in[(size_t)token * 256 + lane * 4];
  float s  = v.x + v.y + v.z + v.w;
  float sq = v.x * v.x + v.y * v.y + v.z * v.z + v.w * v.w;
  #pragma unroll
  for (int m = 1; m < 64; m <<= 1) { s += __shfl_xor(s, m, 64); sq += __shfl_xor(sq, m, 64); }
  const float mean = s * 0.00390625f;
  const float var  = sq * 0.00390625f - mean * mean;
  const float rstd = rsqrtf(var + 1e-5f);
  const float4 wv = *(const float4*)&gw[lane * 4];
  const float4 bv = *(const float4*)&gb[lane * 4];
  int orow;
  if (SHIFTED) {
    const int bb = token >> 16;
    const int h  = (token >> 8) & 255;
    const int w  = token & 255;
    const int hs  = (h - 4) & 255;           // roll(-4)
    const int wsn = (w - 4) & 255;
    orow = (((bb << 10) + ((hs >> 3) << 5) + (wsn >> 3)) << 6) + ((hs & 7) << 3) + (wsn & 7);
  } else {
    orow = token;
  }
  ushort4 o;
  o.x = f2bf((v.x - mean) * rstd * wv.x + bv.x);
  o.y = f2bf((v.y - mean) * rstd * wv.y + bv.y);
  o.z = f2bf((v.z - mean) * rstd * wv.z + bv.z);
  o.w = f2bf((v.w - mean) * rstd * wv.w + bv.w);
  *(ushort4*)&out[(size_t)orow * 256 + lane * 4] = o;
}

// ---------------- bf16 GEMM: C[M,N] = A[M,K] @ W[N,K]^T + bias ----------------
// Staging: global_load_lds width=16, linear LDS dest, pre-swizzled global source
// (rule 21: source permutation == read permutation, both XOR chunk^(row&7)).
// MODE 0: bias->bf16   MODE 1: bias+GELU->bf16
// MODE 2: bias+residual, window-row -> natural-row scatter (roll +4), f32 out
// MODE 3: bias+residual natural rows, f32 out
template<int MODE>
__global__ __launch_bounds__(256)
void gemm_bt(const unsigned short* __restrict__ A, const unsigned short* __restrict__ W,
             const float* __restrict__ bias, int M, int N, int K,
             unsigned short* __restrict__ outB, float* outF, const float* resF)
{
  __shared__ __align__(16) unsigned short As[128 * 64];
  __shared__ __align__(16) unsigned short Bs[128 * 64];
  const int tid  = threadIdx.x;
  const int lane = tid & 63;
  const int wv   = tid >> 6;
  const int n0 = blockIdx.x * 128;
  const int m0 = blockIdx.y * 128;
  const int wm = (wv >> 1) * 64;
  const int wn = (wv & 1) * 64;
  const int lr = lane & 15;
  const int lk = (lane >> 4) * 8;

  const int r8  = lane >> 3;          // row within 8-row stage group
  const int gch = (lane & 7) ^ r8;    // pre-swizzled source chunk

  f32x4 acc[4][4] = {};

  for (int k0 = 0; k0 < K; k0 += 64) {
    #pragma unroll
    for (int s = 0; s < 4; s++) {
      const int rbase = wv * 32 + s * 8;
      gload_lds16(&A[(size_t)(m0 + rbase + r8) * K + k0 + gch * 8], &As[rbase * 64]);
      gload_lds16(&W[(size_t)(n0 + rbase + r8) * K + k0 + gch * 8], &Bs[rbase * 64]);
    }
    __syncthreads();
    #pragma unroll
    for (int kk = 0; kk < 64; kk += 32) {
      short8 af[4], bf[4];
      #pragma unroll
      for (int i = 0; i < 4; i++) {
        const int ra = wm + i * 16 + lr;
        const int rb = wn + i * 16 + lr;
        af[i] = *(const short8*)&As[(ra * 64 + kk + lk) ^ ((ra & 7) << 3)];
        bf[i] = *(const short8*)&Bs[(rb * 64 + kk + lk) ^ ((rb & 7) << 3)];
      }
      #pragma unroll
      for (int i = 0; i < 4; i++)
        #pragma unroll
        for (int j = 0; j < 4; j++)
          acc[i][j] = __builtin_amdgcn_mfma_f32_16x16x32_bf16(af[i], bf[j], acc[i][j], 0, 0, 0);
    }
    __syncthreads();
  }

  // epilogue: C layout col=lane&15, row=(lane>>4)*4+reg
  #pragma unroll
  for (int j = 0; j < 4; j++) {
    const int col = n0 + wn + j * 16 + lr;
    const float bv = bias[col];
    #pragma unroll
    for (int i = 0; i < 4; i++) {
      #pragma unroll
      for (int r = 0; r < 4; r++) {
        const int row = m0 + wm + i * 16 + (lane >> 4) * 4 + r;
        float v = acc[i][j][r] + bv;
        if (MODE == 0) {
          outB[(size_t)row * N + col] = f2bf(v);
        } else if (MODE == 1) {
          float gl = 0.5f * v * (1.0f + erff(v * 0.70710678118654752f));
          outB[(size_t)row * N + col] = f2bf(gl);
        } else if (MODE == 2) {
          const int i6 = row & 63, wn_ = row >> 6;
          const int bb = wn_ >> 10, wi = wn_ & 1023;
          const int hs  = ((wi >> 5) << 3) + (i6 >> 3);
          const int wsn = ((wi & 31) << 3) + (i6 & 7);
          const int hh = (hs + 4) & 255, ww = (wsn + 4) & 255;  // reverse roll (+4)
          const size_t nat = ((size_t)bb << 16) + (hh << 8) + ww;
          outF[nat * 256 + col] = resF[nat * 256 + col] + v;
        } else {
          outF[(size_t)row * N + col] = resF[(size_t)row * N + col] + v;
        }
      }
    }
  }
}

// ---------------- windowed attention, MFMA (1 block = 1 window, 4 waves) ----------------
// Half-head staging: heads 0-3 then 4-7. Wave w owns head half*4+w.
// LDS: Kh 16KB (chunk-XOR swizzle) + Vt 16KB (transposed, swizzled) + P 4x8KB = 64KB.
__global__ __launch_bounds__(256)
void attn_kernel(const unsigned short* __restrict__ Qm, int sq,
                 const unsigned short* __restrict__ Km,
                 const unsigned short* __restrict__ Vm, int skv,
                 const float* __restrict__ mask, const float* __restrict__ biasT,
                 unsigned short* __restrict__ outO)
{
  __shared__ __align__(16) unsigned short Kh[64 * 128];
  __shared__ __align__(16) unsigned short Vth[128 * 64];
  __shared__ __align__(16) unsigned short Ps[4 * 64 * 64];

  const int win = blockIdx.x;
  const int wi  = win & 1023;
  const int tid = threadIdx.x;
  const int lane = tid & 63;
  const int wv  = tid >> 6;
  const int lr = lane & 15;
  const int g  = lane >> 4;
  unsigned short* Pw = &Ps[wv * 4096];

  for (int half = 0; half < 2; half++) {
    // --- stage K half (64 rows x 128 cols) via global_load_lds, source pre-swizzled ---
    {
      const int r_off = g;            // 0..3 rows per 1KB issue
      const int ch    = lane & 15;    // 16B chunk (16 per row)
      #pragma unroll
      for (int s = 0; s < 4; s++) {
        const int row = wv * 16 + s * 4 + r_off;
        const int sch = ch ^ (row & 7);
        gload_lds16(&Km[(size_t)(win * 64 + row) * skv + half * 128 + sch * 8],
                    &Kh[(wv * 16 + s * 4) * 128]);
      }
    }
    // --- stage V transposed (coalesced global read, rotated scalar LDS writes) ---
    #pragma unroll
    for (int it = 0; it < 4; it++) {
      const int slot = tid + it * 256;
      const int tok = slot >> 4;      // 0..63
      const int ch  = slot & 15;      // feature chunk within the 128-col half
      const short8 v8 = *(const short8*)&Vm[(size_t)(win * 64 + tok) * skv + half * 128 + ch * 8];
      #pragma unroll
      for (int es = 0; es < 8; es++) {
        const int e  = (es + ch) & 7;               // rotation diversifies banks
        const int fr = ch * 8 + e;                  // feature row in Vth
        Vth[fr * 64 + (((tok >> 3) ^ (fr & 7)) << 3) + (tok & 7)] = (unsigned short)v8[e];
      }
    }
    __syncthreads();

    const int h = half * 4 + wv;
    // --- QK^T: S(64x64) = Q_h(64x32) @ K_h^T ---
    short8 af[4];
    #pragma unroll
    for (int i = 0; i < 4; i++)
      af[i] = *(const short8*)&Qm[(size_t)(win * 64 + i * 16 + lr) * sq + h * 32 + g * 8];
    f32x4 acc[4][4] = {};
    #pragma unroll
    for (int j = 0; j < 4; j++) {
      const int row = j * 16 + lr;
      const int chn = ((h & 3) * 4 + g) ^ (row & 7);
      const short8 bf = *(const short8*)&Kh[row * 128 + chn * 8];
      #pragma unroll
      for (int i = 0; i < 4; i++)
        acc[i][j] = __builtin_amdgcn_mfma_f32_16x16x32_bf16(af[i], bf, acc[i][j], 0, 0, 0);
    }

    // --- bias + mask + row softmax (rows live in 16-lane groups) ---
    const float* bh = &biasT[h * 4096];
    const float* mh = &mask[(size_t)wi * 4096];
    #pragma unroll
    for (int i = 0; i < 4; i++) {
      #pragma unroll
      for (int r = 0; r < 4; r++) {
        const int row = i * 16 + g * 4 + r;
        #pragma unroll
        for (int j = 0; j < 4; j++) {
          const int col = j * 16 + lr;
          acc[i][j][r] += bh[row * 64 + col] + mh[row * 64 + col];
        }
        float m4 = fmaxf(fmaxf(acc[i][0][r], acc[i][1][r]), fmaxf(acc[i][2][r], acc[i][3][r]));
        #pragma unroll
        for (int mk = 1; mk < 16; mk <<= 1) m4 = fmaxf(m4, __shfl_xor(m4, mk, 64));
        float sum = 0.f;
        #pragma unroll
        for (int j = 0; j < 4; j++) {
          const float e = __expf(acc[i][j][r] - m4);
          acc[i][j][r] = e; sum += e;
        }
        #pragma unroll
        for (int mk = 1; mk < 16; mk <<= 1) sum += __shfl_xor(sum, mk, 64);
        const float inv = 1.f / sum;
        #pragma unroll
        for (int j = 0; j < 4; j++) {
          const int col = j * 16 + lr;
          Pw[row * 64 + (((col >> 3) ^ (row & 7)) << 3) + (col & 7)] = f2bf(acc[i][j][r] * inv);
        }
      }
    }

    // --- PV: O(64x32) = P(64x64) @ V_h(64x32), B-operand = Vth rows ---
    f32x4 o[4][2] = {};
    #pragma unroll
    for (int kk = 0; kk < 2; kk++) {
      short8 bv[2];
      #pragma unroll
      for (int jj = 0; jj < 2; jj++) {
        const int frow = (h & 3) * 32 + jj * 16 + lr;
        const int chn = (kk * 4 + g) ^ (frow & 7);
        bv[jj] = *(const short8*)&Vth[frow * 64 + chn * 8];
      }
      #pragma unroll
      for (int i = 0; i < 4; i++) {
        const int prow = i * 16 + lr;
        const int chn = (kk * 4 + g) ^ (prow & 7);
        const short8 pa = *(const short8*)&Pw[prow * 64 + chn * 8];
        #pragma unroll
        for (int jj = 0; jj < 2; jj++)
          o[i][jj] = __builtin_amdgcn_mfma_f32_16x16x32_bf16(pa, bv[jj], o[i][jj], 0, 0, 0);
      }
    }
    // --- write O (P pre-normalized) ---
    #pragma unroll
    for (int i = 0; i < 4; i++)
      #pragma unroll
      for (int jj = 0; jj < 2; jj++)
        #pragma unroll
        for (int r = 0; r < 4; r++) {
          const int row = i * 16 + g * 4 + r;
          outO[(size_t)(win * 64 + row) * 256 + h * 32 + jj * 16 + lr] = f2bf(o[i][jj][r]);
        }
    __syncthreads();
  }
}

// ---------------- launch ----------------
extern "C" void kernel_launch(void* const* d_in, const int* in_sizes, int n_in,
                              void* d_out, int out_size, void* d_ws, size_t ws_size,
                              hipStream_t stream)
{
  const float* x       = (const float*)d_in[0];
  const float* akv     = (const float*)d_in[1];
  const float* mask_q  = (const float*)d_in[2];
  const float* mask_kv = (const float*)d_in[3];
  const float* n1w = (const float*)d_in[4];
  const float* n1b = (const float*)d_in[5];
  const float* n2w = (const float*)d_in[6];
  const float* n2b = (const float*)d_in[7];
  const float* n3w = (const float*)d_in[8];
  const float* n3b = (const float*)d_in[9];
  const float* nkvw = (const float*)d_in[10];
  const float* nkvb = (const float*)d_in[11];

  char* ws = (char*)d_ws;
  const unsigned short* WQKV1 = (const unsigned short*)(ws + OFF_WQKV1);
  const float*          BQKV1 = (const float*)(ws + OFF_BQKV1);
  const unsigned short* WQ2   = (const unsigned short*)(ws + OFF_WQ2);
  const float*          BQ2   = (const float*)(ws + OFF_BQ2);
  const unsigned short* WKV2  = (const unsigned short*)(ws + OFF_WKV2);
  const float*          BKV2  = (const float*)(ws + OFF_BKV2);
  const unsigned short* WP1   = (const unsigned short*)(ws + OFF_WP1);
  const float*          BP1   = (const float*)(ws + OFF_BP1);
  const unsigned short* WP2   = (const unsigned short*)(ws + OFF_WP2);
  const float*          BP2   = (const float*)(ws + OFF_BP2);
  const unsigned short* WFC1  = (const unsigned short*)(ws + OFF_WFC1);
  const float*          BFC1  = (const float*)(ws + OFF_BFC1);
  const unsigned short* WFC2  = (const unsigned short*)(ws + OFF_WFC2);
  const float*          BFC2  = (const float*)(ws + OFF_BFC2);
  const float* BIAS1 = (const float*)(ws + OFF_BIAS1);
  const float* BIAS2 = (const float*)(ws + OFF_BIAS2);

  float*          x1  = (float*)(ws + OFF_X1);
  unsigned short* qkv = (unsigned short*)(ws + OFF_QKV);
  unsigned short* kv2 = (unsigned short*)(ws + OFF_KV2);
  unsigned short* hB  = (unsigned short*)(ws + OFF_HB);
  unsigned short* hA  = (unsigned short*)(ws + OFF_HA);
  float* out = (float*)d_out;

  prep_kernel<<<4365, 256, 0, stream>>>(
      (const float*)d_in[12], (const float*)d_in[13], (const float*)d_in[14], (const float*)d_in[15],
      (const float*)d_in[16], (const float*)d_in[17], (const float*)d_in[18],
      (const float*)d_in[19], (const float*)d_in[20], (const float*)d_in[21], (const float*)d_in[22],
      (const float*)d_in[23], (const float*)d_in[24], (const float*)d_in[25],
      (const float*)d_in[26], (const float*)d_in[27], (const float*)d_in[28], (const float*)d_in[29],
      ws);

  // ---- shifted-window self attention ----
  ln_kernel<1><<<32768, 256, 0, stream>>>(x, n1w, n1b, hA);
  gemm_bt<0><<<dim3(6, 1024), 256, 0, stream>>>(hA, WQKV1, BQKV1, 131072, 768, 256, qkv, nullptr, nullptr);
  attn_kernel<<<2048, 256, 0, stream>>>(qkv, 768, qkv + 256, qkv + 512, 768, mask_q, BIAS1, hA);
  gemm_bt<2><<<dim3(2, 1024), 256, 0, stream>>>(hA, WP1, BP1, 131072, 256, 256, nullptr, x1, x);

  // ---- shifted-window cross attention ----
  ln_kernel<1><<<32768, 256, 0, stream>>>(x1, n2w, n2b, hA);
  ln_kernel<1><<<32768, 256, 0, stream>>>(akv, nkvw, nkvb, hB);
  gemm_bt<0><<<dim3(2, 1024), 256, 0, stream>>>(hA, WQ2, BQ2, 131072, 256, 256, qkv, nullptr, nullptr);
  gemm_bt<0><<<dim3(4, 1024), 256, 0, stream>>>(hB, WKV2, BKV2, 131072, 512, 256, kv2, nullptr, nullptr);
  attn_kernel<<<2048, 256, 0, stream>>>(qkv, 256, kv2, kv2 + 256, 512, mask_kv, BIAS2, hA);
  gemm_bt<2><<<dim3(2, 1024), 256, 0, stream>>>(hA, WP2, BP2, 131072, 256, 256, nullptr, out, x1);

  // ---- MLP ----
  ln_kernel<0><<<32768, 256, 0, stream>>>(out, n3w, n3b, hA);
  gemm_bt<1><<<dim3(8, 1024), 256, 0, stream>>>(hA, WFC1, BFC1, 131072, 1024, 256, qkv, nullptr, nullptr);
  gemm_bt<3><<<dim3(2, 1024), 256, 0, stream>>>(qkv, WFC2, BFC2, 131072, 256, 1024, nullptr, out, out);
}